// Round 1
// baseline (156.395 us; speedup 1.0000x reference)
//
#include <hip/hip_runtime.h>
#include <hip/hip_fp16.h>

// GAT: B=2, N=4096, F=512, H=8, d=o=64, alpha=0.2
// out[b,n,h*64+c] = elu( sum_m softmax_m(lrelu(f[n]+g[m])) * Wh[m,c] )
// f = Wh.a1, g = Wh.a2 ; row max is EXACT via monotonicity: lrelu(f + max g).

#define NB   2
#define NN   4096
#define NH   8
#define ND   64
#define ALPHA 0.2f
#define LOG2E 1.4426950408889634f

typedef _Float16 f16x8 __attribute__((ext_vector_type(8)));
typedef float    f32x4 __attribute__((ext_vector_type(4)));

__device__ __forceinline__ float fast_exp2(float x) {
#if __has_builtin(__builtin_amdgcn_exp2f)
    return __builtin_amdgcn_exp2f(x);
#else
    return exp2f(x);
#endif
}

// ---------------------------------------------------------------------------
// Kernel 1: per (b,h), 64-row tile: Wh = h_tile @ W[h]  (fp32 vector GEMM)
// writes: Wh_t fp16 [bh][c][n] (transposed), f' = (Wh.a1)*log2e, g' = (Wh.a2)*log2e
// grid: 16 bh * 64 tiles = 1024 blocks, 256 threads
// ---------------------------------------------------------------------------
__global__ __launch_bounds__(256) void k_wh(
    const float* __restrict__ hsrc, const float* __restrict__ W,
    const float* __restrict__ a,
    _Float16* __restrict__ Wh_t, float* __restrict__ fb, float* __restrict__ gb)
{
    const int bid  = blockIdx.x;
    const int tile = bid & 63;
    const int bh   = bid >> 6;
    const int hh   = bh & 7;
    const int b    = bh >> 3;
    const int n0   = tile * 64;
    const int t    = threadIdx.x;

    __shared__ float Wl[64 * 68];   // W[h] staged, [k][c], pad 68 (row=272B, 16B-aligned)
    __shared__ float ht[64 * 68];   // h tile transposed [k][r]; reused as fp16 wt[c][r] later
    __shared__ float red[2 * 64 * 16];

    // stage W[hh] (64x64 fp32)
    {
        const float* Wg = W + hh * 4096;
        #pragma unroll
        for (int p = 0; p < 4; p++) {
            int idx = (t + p * 256) * 4;          // 0..4092
            float4 v = *(const float4*)(Wg + idx);
            int k = idx >> 6, c = idx & 63;
            *(float4*)(&Wl[k * 68 + c]) = v;
        }
    }
    // stage h tile transposed: ht[k][r]
    {
        #pragma unroll
        for (int p = 0; p < 4; p++) {
            int r  = (t >> 4) + p * 16;
            int kq = (t & 15) * 4;
            const float* src = hsrc + ((size_t)(b * NN + n0 + r)) * 512 + hh * 64 + kq;
            float4 v = *(const float4*)src;
            ht[(kq + 0) * 68 + r] = v.x;
            ht[(kq + 1) * 68 + r] = v.y;
            ht[(kq + 2) * 68 + r] = v.z;
            ht[(kq + 3) * 68 + r] = v.w;
        }
    }
    __syncthreads();

    const int rq = t >> 4, cq = t & 15;   // 16x16 threads -> 4x4 outputs each
    float acc[4][4] = {};
    for (int k = 0; k < 64; k++) {
        float4 hv = *(const float4*)(&ht[k * 68 + rq * 4]);
        float4 wv = *(const float4*)(&Wl[k * 68 + cq * 4]);
        const float* hp = (const float*)&hv;
        const float* wp = (const float*)&wv;
        #pragma unroll
        for (int i = 0; i < 4; i++)
            #pragma unroll
            for (int j = 0; j < 4; j++)
                acc[i][j] = fmaf(hp[i], wp[j], acc[i][j]);
    }

    float a1v[4], a2v[4];
    {
        const float* ag = a + hh * 128;
        #pragma unroll
        for (int j = 0; j < 4; j++) { a1v[j] = ag[cq * 4 + j]; a2v[j] = ag[64 + cq * 4 + j]; }
    }
    __syncthreads();                 // all ht reads done -> safe to reuse as wt

    _Float16* wt = (_Float16*)ht;    // [c][64 rows]
    #pragma unroll
    for (int i = 0; i < 4; i++) {
        float fp = 0.f, gp = 0.f;
        #pragma unroll
        for (int j = 0; j < 4; j++) {
            fp = fmaf(acc[i][j], a1v[j], fp);
            gp = fmaf(acc[i][j], a2v[j], gp);
        }
        red[0 * 1024 + (rq * 4 + i) * 16 + cq] = fp;
        red[1 * 1024 + (rq * 4 + i) * 16 + cq] = gp;
        #pragma unroll
        for (int j = 0; j < 4; j++)
            wt[(cq * 4 + j) * 64 + rq * 4 + i] = (_Float16)acc[i][j];
    }
    __syncthreads();

    if (t < 128) {                   // reduce f/g over the 16 col-threads
        int which = t >> 6, row = t & 63;
        const float* rr = &red[which * 1024 + row * 16];
        float s = 0.f;
        #pragma unroll
        for (int j = 0; j < 16; j++) s += rr[j];
        s *= LOG2E;                  // store pre-scaled into log2 domain
        float* dst = which ? gb : fb;
        dst[(size_t)bh * NN + n0 + row] = s;
    }
    // coalesced fp16 transposed write: Wh_t[bh][c][n0..n0+63]
    #pragma unroll
    for (int p = 0; p < 2; p++) {
        int idx = t + p * 256;       // 0..511 = 64 c * 8 segs
        int c = idx >> 3, seg = idx & 7;
        float4 v = *(const float4*)(&wt[c * 64 + seg * 8]);
        *(float4*)(Wh_t + (size_t)bh * 64 * NN + (size_t)c * NN + n0 + seg * 8) = v;
    }
}

// ---------------------------------------------------------------------------
// Kernel G: G'[bh] = max_m g'[bh][m]   (exact row-max enabler)
// ---------------------------------------------------------------------------
__global__ __launch_bounds__(256) void k_gmax(const float* __restrict__ gb,
                                              float* __restrict__ G)
{
    int bh = blockIdx.x, t = threadIdx.x;
    const float* g = gb + (size_t)bh * NN;
    float v = -1e30f;
    for (int i = t; i < NN; i += 256) v = fmaxf(v, g[i]);
    #pragma unroll
    for (int s = 1; s < 64; s <<= 1) v = fmaxf(v, __shfl_xor(v, s, 64));
    __shared__ float wmax[4];
    if ((t & 63) == 0) wmax[t >> 6] = v;
    __syncthreads();
    if (t == 0) G[bh] = fmaxf(fmaxf(wmax[0], wmax[1]), fmaxf(wmax[2], wmax[3]));
}

// ---------------------------------------------------------------------------
// Kernel 2: attention. 512 blocks (16 bh x 32 tiles of 128 rows), 256 thr.
// Wave w owns 32 rows (2 row-groups of 16). P generated directly in A-frag
// layout (row=lane&15, k=(lane>>4)*8+j). B staged [64c][64m] fp16 in LDS with
// XOR slot swizzle (slot = gi ^ (c&7)) -> conflict-free ds_read_b128.
// ---------------------------------------------------------------------------
__global__ __launch_bounds__(256) void k_attn(
    const _Float16* __restrict__ Wh_t, const float* __restrict__ fb,
    const float* __restrict__ gb, const float* __restrict__ G,
    float* __restrict__ out)
{
    const int bid   = blockIdx.x;
    const int ntile = bid & 31;
    const int bh    = bid >> 5;
    const int hh    = bh & 7;
    const int b     = bh >> 3;
    const int n0    = ntile * 128;
    const int t     = threadIdx.x;
    const int w     = t >> 6;
    const int l     = t & 63;
    const int lr    = l & 15;        // A row / B col / D col lane index
    const int lg    = l >> 4;        // k-group

    const _Float16* Wp = Wh_t + (size_t)bh * 64 * NN;
    const float*    gp = gb + (size_t)bh * NN;
    const float*    fp = fb + (size_t)bh * NN;
    const float     Gv = G[bh];

    // per-lane row constants (scaled domain): arg = max(c1+g', fma(.2,g',c2))
    float c1[2], c2[2];
    #pragma unroll
    for (int rg = 0; rg < 2; rg++) {
        int rn = n0 + w * 32 + rg * 16 + lr;
        float f = fp[rn];
        float s = f + Gv;
        float Mxl = fmaxf(s, ALPHA * s);     // exact row max (scaled)
        c1[rg] = f - Mxl;
        c2[rg] = fmaf(ALPHA, f, -Mxl);
    }

    f32x4 acc[2][4];
    #pragma unroll
    for (int rg = 0; rg < 2; rg++)
        #pragma unroll
        for (int ct = 0; ct < 4; ct++) acc[rg][ct] = (f32x4){0.f, 0.f, 0.f, 0.f};
    float dsum[2] = {0.f, 0.f};

    __shared__ _Float16 __attribute__((aligned(16))) Bt[64 * 64];  // 8 KB
    __shared__ float dn[128];

    // register prefetch of chunk-0 staging granules
    float4 pre[2];
    {
        #pragma unroll
        for (int i = 0; i < 2; i++) {
            int idx = t + i * 256; int c = idx >> 3, s = idx & 7;
            int gi = s ^ (c & 7);
            pre[i] = *(const float4*)(Wp + (size_t)c * NN + 0 + gi * 8);
        }
    }

    for (int ch = 0; ch < 64; ch++) {
        // publish staged tile
        #pragma unroll
        for (int i = 0; i < 2; i++) {
            int idx = t + i * 256; int c = idx >> 3, s = idx & 7;
            *(float4*)((char*)Bt + c * 128 + s * 16) = pre[i];
        }
        __syncthreads();

        // prefetch next chunk (overlaps with compute below)
        if (ch < 63) {
            int m0n = (ch + 1) * 64;
            #pragma unroll
            for (int i = 0; i < 2; i++) {
                int idx = t + i * 256; int c = idx >> 3, s = idx & 7;
                int gi = s ^ (c & 7);
                pre[i] = *(const float4*)(Wp + (size_t)c * NN + m0n + gi * 8);
            }
        }

        // B fragments: col = ct*16+lr, k granule gi = kh*4+lg (swizzled slot)
        f16x8 bf[2][4];
        #pragma unroll
        for (int kh = 0; kh < 2; kh++)
            #pragma unroll
            for (int ct = 0; ct < 4; ct++) {
                int c  = ct * 16 + lr;
                int gi = kh * 4 + lg;
                bf[kh][ct] = *(const f16x8*)((const char*)Bt + c * 128 + ((gi ^ (c & 7)) * 16));
            }

        const int m0 = ch * 64;
        #pragma unroll
        for (int kh = 0; kh < 2; kh++) {
            // 8 g' values for this lane's k slots (L1-broadcast across col groups)
            const float* gsrc = gp + m0 + kh * 32 + lg * 8;
            float4 g0 = *(const float4*)gsrc;
            float4 g1 = *(const float4*)(gsrc + 4);
            float gv[8] = {g0.x, g0.y, g0.z, g0.w, g1.x, g1.y, g1.z, g1.w};

            #pragma unroll
            for (int rg = 0; rg < 2; rg++) {
                f16x8 af;
                float ds = 0.f;
                #pragma unroll
                for (int j = 0; j < 8; j++) {
                    float aa = c1[rg] + gv[j];
                    float bb = fmaf(ALPHA, gv[j], c2[rg]);
                    float p  = fast_exp2(fmaxf(aa, bb));
                    ds += p;
                    af[j] = (_Float16)p;
                }
                dsum[rg] += ds;
                #pragma unroll
                for (int ct = 0; ct < 4; ct++)
                    acc[rg][ct] = __builtin_amdgcn_mfma_f32_16x16x32_f16(
                        af, bf[kh][ct], acc[rg][ct], 0, 0, 0);
            }
        }
        __syncthreads();
    }

    // denominator: sum over the 4 k-groups per row
    #pragma unroll
    for (int rg = 0; rg < 2; rg++) {
        float d = dsum[rg];
        d += __shfl_xor(d, 16, 64);
        d += __shfl_xor(d, 32, 64);
        if (lg == 0) dn[w * 32 + rg * 16 + lr] = d;
    }
    __syncthreads();

    // epilogue: D layout col=lane&15, row=(lane>>4)*4+reg
    float* outp = out + ((size_t)(b * NN + n0)) * 512 + hh * 64;
    #pragma unroll
    for (int rg = 0; rg < 2; rg++)
        #pragma unroll
        for (int reg = 0; reg < 4; reg++) {
            int rl = w * 32 + rg * 16 + lg * 4 + reg;
            float rinv = 1.0f / dn[rl];
            #pragma unroll
            for (int ct = 0; ct < 4; ct++) {
                float v = acc[rg][ct][reg] * rinv;
                v = v > 0.f ? v : fast_exp2(v * LOG2E) - 1.f;   // elu
                outp[(size_t)rl * 512 + ct * 16 + lr] = v;
            }
        }
}

// ---------------------------------------------------------------------------
extern "C" void kernel_launch(void* const* d_in, const int* in_sizes, int n_in,
                              void* d_out, int out_size, void* d_ws, size_t ws_size,
                              hipStream_t stream)
{
    const float* hsrc = (const float*)d_in[0];
    const float* W    = (const float*)d_in[1];
    const float* a    = (const float*)d_in[2];
    float* outp       = (float*)d_out;

    // workspace layout
    const size_t WHT_BYTES = (size_t)NB * NH * 64 * NN * sizeof(_Float16); // 8 MB
    const size_t FG_BYTES  = (size_t)NB * NH * NN * sizeof(float);         // 256 KB each
    const size_t NEED = WHT_BYTES + 2 * FG_BYTES + 64 * sizeof(float);
    if (ws_size < NEED) return;  // safety: avoid OOB scratch writes

    char* ws = (char*)d_ws;
    _Float16* Wh_t = (_Float16*)ws;
    float*    fbuf = (float*)(ws + WHT_BYTES);
    float*    gbuf = (float*)(ws + WHT_BYTES + FG_BYTES);
    float*    Gmax = (float*)(ws + WHT_BYTES + 2 * FG_BYTES);

    k_wh  <<<dim3(NB * NH * (NN / 64)), dim3(256), 0, stream>>>(hsrc, W, a, Wh_t, fbuf, gbuf);
    k_gmax<<<dim3(NB * NH),             dim3(256), 0, stream>>>(gbuf, Gmax);
    k_attn<<<dim3(NB * NH * (NN / 128)), dim3(256), 0, stream>>>(Wh_t, fbuf, gbuf, Gmax, outp);
}

// Round 3
// 89.321 us; speedup vs baseline: 1.7509x; 1.7509x over previous
//
#include <hip/hip_runtime.h>
#include <hip/hip_fp16.h>

// GAT: B=2, N=4096, F=512, H=8, d=o=64, alpha=0.2
// out[b,n,h*64+c] = elu( sum_m softmax_m(lrelu(f[n]+g[m])) * Wh[m,c] )
// Factorized scores: p = max(Ef[n]*Eg[m], Ff[n]*Fg[m]), all factors in (0,1] -> fp16,
// zero transcendentals in the O(N^2) loop. Denominator via ones-column MFMA.

#define NB   2
#define NN   4096
#define NH   8
#define ALPHA 0.2f
#define LOG2E 1.4426950408889634f

typedef _Float16 f16x8 __attribute__((ext_vector_type(8)));
typedef float    f32x4 __attribute__((ext_vector_type(4)));

__device__ __forceinline__ void gload_lds16(const _Float16* g, void* lds) {
    __builtin_amdgcn_global_load_lds((const __attribute__((address_space(1))) void*)g,
                                     (__attribute__((address_space(3))) void*)lds, 16, 0, 0);
}

__device__ __forceinline__ f16x8 splat8(float x) {
    _Float16 h = (_Float16)x;
    f16x8 v;
    #pragma unroll
    for (int j = 0; j < 8; j++) v[j] = h;
    return v;
}

// ---------------------------------------------------------------------------
// Kernel 1: per (b,h), 64-row tile: Wh = h_tile @ W[h]  (fp32 vector GEMM)
// ht staged [r][k] (coalesced, conflict-free); compute reads h via b32
// broadcasts (16 same-addr lanes) + W via b128. Outputs: Wh_t fp16 [bh][c][n],
// f' = (Wh.a1)*log2e, g' = (Wh.a2)*log2e.
// ---------------------------------------------------------------------------
__global__ __launch_bounds__(256) void k_wh(
    const float* __restrict__ hsrc, const float* __restrict__ W,
    const float* __restrict__ a,
    _Float16* __restrict__ Wh_t, float* __restrict__ fb, float* __restrict__ gb)
{
    const int bid  = blockIdx.x;
    const int tile = bid & 63;
    const int bh   = bid >> 6;
    const int hh   = bh & 7;
    const int b    = bh >> 3;
    const int n0   = tile * 64;
    const int t    = threadIdx.x;

    __shared__ float Wl[64 * 68];   // [k][c] pad 68
    __shared__ float ht[64 * 68];   // [r][k] pad 68; reused as fp16 wt[c][64] later
    __shared__ float red[2 * 64 * 16];

    // stage W[hh] (64x64 fp32), [k][c]
    {
        const float* Wg = W + hh * 4096;
        #pragma unroll
        for (int p = 0; p < 4; p++) {
            int idx = (t + p * 256) * 4;
            float4 v = *(const float4*)(Wg + idx);
            int k = idx >> 6, c = idx & 63;
            *(float4*)(&Wl[k * 68 + c]) = v;
        }
    }
    // stage h tile [r][k] (direct, coalesced)
    {
        #pragma unroll
        for (int p = 0; p < 4; p++) {
            int idx = t + p * 256;           // 0..1023 float4 granules
            int r = idx >> 4, kq = (idx & 15) * 4;
            float4 v = *(const float4*)(hsrc + ((size_t)(b * NN + n0 + r)) * 512 + hh * 64 + kq);
            *(float4*)(&ht[r * 68 + kq]) = v;
        }
    }
    __syncthreads();

    const int rq = t >> 4, cq = t & 15;
    float acc[4][4] = {};
    for (int k = 0; k < 64; k++) {
        float4 wv = *(const float4*)(&Wl[k * 68 + cq * 4]);
        float hv[4];
        #pragma unroll
        for (int i = 0; i < 4; i++) hv[i] = ht[(rq * 4 + i) * 68 + k];  // broadcast
        const float* wp = (const float*)&wv;
        #pragma unroll
        for (int i = 0; i < 4; i++)
            #pragma unroll
            for (int j = 0; j < 4; j++)
                acc[i][j] = fmaf(hv[i], wp[j], acc[i][j]);
    }

    float a1v[4], a2v[4];
    {
        const float* ag = a + hh * 128;
        #pragma unroll
        for (int j = 0; j < 4; j++) { a1v[j] = ag[cq * 4 + j]; a2v[j] = ag[64 + cq * 4 + j]; }
    }
    __syncthreads();                 // all ht reads done -> reuse as wt

    _Float16* wt = (_Float16*)ht;    // [c][64 rows]
    #pragma unroll
    for (int i = 0; i < 4; i++) {
        float fp = 0.f, gp = 0.f;
        #pragma unroll
        for (int j = 0; j < 4; j++) {
            fp = fmaf(acc[i][j], a1v[j], fp);
            gp = fmaf(acc[i][j], a2v[j], gp);
        }
        red[0 * 1024 + (rq * 4 + i) * 16 + cq] = fp;
        red[1 * 1024 + (rq * 4 + i) * 16 + cq] = gp;
        #pragma unroll
        for (int j = 0; j < 4; j++)
            wt[(cq * 4 + j) * 64 + rq * 4 + i] = (_Float16)acc[i][j];
    }
    __syncthreads();

    if (t < 128) {
        int which = t >> 6, row = t & 63;
        const float* rr = &red[which * 1024 + row * 16];
        float s = 0.f;
        #pragma unroll
        for (int j = 0; j < 16; j++) s += rr[j];
        s *= LOG2E;                  // log2 domain
        float* dst = which ? gb : fb;
        dst[(size_t)bh * NN + n0 + row] = s;
    }
    #pragma unroll
    for (int p = 0; p < 2; p++) {
        int idx = t + p * 256;
        int c = idx >> 3, seg = idx & 7;
        float4 v = *(const float4*)(&wt[c * 64 + seg * 8]);
        *(float4*)(Wh_t + (size_t)bh * 64 * NN + (size_t)c * NN + n0 + seg * 8) = v;
    }
}

// ---------------------------------------------------------------------------
// Kernel prep: per bh: G = max g'; Eg = 2^(g-G), Fg = 2^(alpha*(g-G)) fp16.
// Eg/Fg ALIAS the g storage (per-bh 16KB chunk): all g reads into regs first.
// ---------------------------------------------------------------------------
__global__ __launch_bounds__(256) void k_prep(const float* __restrict__ gball,
                                              float* __restrict__ G,
                                              char* __restrict__ egfg_base)
{
    int bh = blockIdx.x, t = threadIdx.x;
    const float* g = gball + (size_t)bh * NN;
    float vals[16];
    float m = -1e30f;
    #pragma unroll
    for (int j = 0; j < 16; j++) { vals[j] = g[t + j * 256]; m = fmaxf(m, vals[j]); }
    #pragma unroll
    for (int s = 1; s < 64; s <<= 1) m = fmaxf(m, __shfl_xor(m, s, 64));
    __shared__ float wm[4];
    if ((t & 63) == 0) wm[t >> 6] = m;
    __syncthreads();                 // also: all g loads complete before aliased writes
    float Gv = fmaxf(fmaxf(wm[0], wm[1]), fmaxf(wm[2], wm[3]));
    if (t == 0) G[bh] = Gv;
    _Float16* Eg = (_Float16*)(egfg_base + (size_t)bh * 16384);
    _Float16* Fg = Eg + NN;
    #pragma unroll
    for (int j = 0; j < 16; j++) {
        int i = t + j * 256;
        float d = vals[j] - Gv;      // <= 0
        Eg[i] = (_Float16)exp2f(d);
        Fg[i] = (_Float16)exp2f(ALPHA * d);
    }
}

// ---------------------------------------------------------------------------
// Kernel 2: attention. 512 blocks x 512 threads. Block: 128 rows x 64 cols.
// 8 waves as 4(row) x 2(col); wave-tile 32x32 via 2x2 of 16x16x32 MFMA.
// Double-buffered LDS B-tile [64c][64m] fp16 via global_load_lds (linear dest,
// XOR-swizzled source granules); one barrier per chunk. Scores: packed fp16
// max(Eg*Ef, Fg*Ff) via v_pk_mul/v_pk_max. Row-sums via ones-B MFMA (accd).
// ---------------------------------------------------------------------------
__global__ __launch_bounds__(512, 4) void k_attn(
    const _Float16* __restrict__ Wh_t, const float* __restrict__ fb,
    const float* __restrict__ G, const char* __restrict__ egfg_base,
    float* __restrict__ out)
{
    // XCD-bijective swizzle: 512 = 8 XCD x 64; XCD x owns 2 full bh slices.
    const int orig  = blockIdx.x;
    const int bid   = (orig & 7) * 64 + (orig >> 3);
    const int ntile = bid & 31;
    const int bh    = bid >> 5;
    const int hh    = bh & 7;
    const int b     = bh >> 3;
    const int n0    = ntile * 128;
    const int t     = threadIdx.x;
    const int w     = t >> 6;
    const int wr    = w >> 1;        // 0..3 row-wave
    const int wc    = w & 1;         // 0..1 col-wave
    const int l     = t & 63;
    const int lr    = l & 15;
    const int lg    = l >> 4;

    const _Float16* Wp  = Wh_t + (size_t)bh * 64 * NN;
    const _Float16* Egp = (const _Float16*)(egfg_base + (size_t)bh * 16384);
    const float     Gv  = G[bh];

    // per-row factors (one of Ef,Ff is exactly 1)
    f16x8 ef8[2], ff8[2];
    #pragma unroll
    for (int rg = 0; rg < 2; rg++) {
        int rn = n0 + wr * 32 + rg * 16 + lr;
        float s  = fb[(size_t)bh * NN + rn] + Gv;
        float t1 = (1.f - ALPHA) * s;
        ef8[rg] = splat8(exp2f(fminf(t1, 0.f)));
        ff8[rg] = splat8(exp2f(fminf(-t1, 0.f)));
    }

    f32x4 acc[2][2];
    f32x4 accd[2];
    #pragma unroll
    for (int rg = 0; rg < 2; rg++) {
        accd[rg] = (f32x4){0.f, 0.f, 0.f, 0.f};
        #pragma unroll
        for (int ct = 0; ct < 2; ct++) acc[rg][ct] = (f32x4){0.f, 0.f, 0.f, 0.f};
    }
    const f16x8 onesv = splat8(1.0f);

    __shared__ _Float16 __attribute__((aligned(16))) Bt[2][64 * 64];  // 16 KB

    // staging addressing: thread t owns granule t: c=t>>3, slot=t&7,
    // source granule gi = slot ^ (c&7) (read applies same involution)
    const int c_s  = t >> 3;
    const int gi_s = (t & 7) ^ (c_s & 7);
    const _Float16* gsrc = Wp + (size_t)c_s * NN + gi_s * 8;
    char* lds0 = (char*)Bt + w * 1024;   // + lane*16 done by HW

    gload_lds16(gsrc, lds0);             // chunk 0 -> buf 0
    __syncthreads();

    for (int ch = 0; ch < 64; ch++) {
        const int cur = ch & 1;
        if (ch < 63) gload_lds16(gsrc + (ch + 1) * 64, lds0 + (cur ^ 1) * 8192);

        const _Float16* bt = (const _Float16*)((const char*)Bt + cur * 8192);
        f16x8 bfr[2][2];
        #pragma unroll
        for (int kh = 0; kh < 2; kh++)
            #pragma unroll
            for (int ct = 0; ct < 2; ct++) {
                int cl   = wc * 32 + ct * 16 + lr;
                int slot = (kh * 4 + lg) ^ (cl & 7);
                bfr[kh][ct] = *(const f16x8*)(bt + cl * 64 + slot * 8);
            }

        f16x8 egv[2], fgv[2];
        #pragma unroll
        for (int kh = 0; kh < 2; kh++) {
            const _Float16* ep = Egp + ch * 64 + kh * 32 + lg * 8;
            egv[kh] = *(const f16x8*)ep;
            fgv[kh] = *(const f16x8*)(ep + NN);
        }

        #pragma unroll
        for (int kh = 0; kh < 2; kh++)
            #pragma unroll
            for (int rg = 0; rg < 2; rg++) {
                f16x8 pa = egv[kh] * ef8[rg];          // v_pk_mul_f16
                f16x8 pb = fgv[kh] * ff8[rg];
                f16x8 af = __builtin_elementwise_max(pa, pb);  // v_pk_max_f16
                #pragma unroll
                for (int ct = 0; ct < 2; ct++)
                    acc[rg][ct] = __builtin_amdgcn_mfma_f32_16x16x32_f16(
                        af, bfr[kh][ct], acc[rg][ct], 0, 0, 0);
                accd[rg] = __builtin_amdgcn_mfma_f32_16x16x32_f16(
                    af, onesv, accd[rg], 0, 0, 0);
            }
        __syncthreads();
    }

    // epilogue: D row = lg*4+reg, col = ct*16+lr ; denominator in-lane (accd)
    float* outp = out + ((size_t)(b * NN + n0)) * 512 + hh * 64 + wc * 32;
    #pragma unroll
    for (int rg = 0; rg < 2; rg++)
        #pragma unroll
        for (int reg = 0; reg < 4; reg++) {
            int rl = wr * 32 + rg * 16 + lg * 4 + reg;
            float rinv = 1.0f / accd[rg][reg];
            #pragma unroll
            for (int ct = 0; ct < 2; ct++) {
                float v = acc[rg][ct][reg] * rinv;
                v = v > 0.f ? v : (exp2f(v * LOG2E) - 1.f);   // elu
                outp[(size_t)rl * 512 + ct * 16 + lr] = v;
            }
        }
}

// ---------------------------------------------------------------------------
extern "C" void kernel_launch(void* const* d_in, const int* in_sizes, int n_in,
                              void* d_out, int out_size, void* d_ws, size_t ws_size,
                              hipStream_t stream)
{
    const float* hsrc = (const float*)d_in[0];
    const float* W    = (const float*)d_in[1];
    const float* a    = (const float*)d_in[2];
    float* outp       = (float*)d_out;

    const size_t WHT_BYTES = (size_t)NB * NH * 64 * NN * sizeof(_Float16); // 8 MB
    const size_t FB_BYTES  = (size_t)NB * NH * NN * sizeof(float);         // 256 KB
    const size_t GB_BYTES  = (size_t)NB * NH * NN * sizeof(float);         // 256 KB (g', later Eg/Fg)
    const size_t NEED = WHT_BYTES + FB_BYTES + GB_BYTES + 64 * sizeof(float);
    if (ws_size < NEED) return;

    char* ws = (char*)d_ws;
    _Float16* Wh_t = (_Float16*)ws;
    float*    fbuf = (float*)(ws + WHT_BYTES);
    char*     gbase = ws + WHT_BYTES + FB_BYTES;            // [bh][16KB]: g' f32 -> Eg|Fg fp16
    float*    Gmax = (float*)(ws + WHT_BYTES + FB_BYTES + GB_BYTES);

    k_wh  <<<dim3(NB * NH * (NN / 64)),  dim3(256), 0, stream>>>(hsrc, W, a, Wh_t, fbuf, (float*)gbase);
    k_prep<<<dim3(NB * NH),              dim3(256), 0, stream>>>((const float*)gbase, Gmax, gbase);
    k_attn<<<dim3(NB * NH * (NN / 128)), dim3(512), 0, stream>>>(Wh_t, fbuf, Gmax, gbase, outp);
}

// Round 4
// 71.909 us; speedup vs baseline: 2.1749x; 1.2421x over previous
//
#include <hip/hip_runtime.h>
#include <hip/hip_fp16.h>

// GAT: B=2, N=4096, F=512, H=8, d=o=64, alpha=0.2
// out[b,n,h*64+c] = elu( sum_m softmax_m(lrelu(f[n]+g[m])) * Wh[m,c] )
// Factorized scores p = max(Ef[n]*Eg[m], Ff[n]*Fg[m]) (all in (0,1], fp16,
// zero transcendentals in O(N^2)). Denominator via v_dot2_f32_f16.
// k_attn: 128rx64c blocks, 8 waves = 4(kg: m-split) x 2(wr: row-split);
// k-split cuts LDS B-re-read 4x; kg-partials reduced through LDS at the end.

#define NB   2
#define NN   4096
#define NH   8
#define ALPHA 0.2f
#define LOG2E 1.4426950408889634f

typedef _Float16 f16x8 __attribute__((ext_vector_type(8)));
typedef _Float16 f16x2 __attribute__((ext_vector_type(2)));
typedef float    f32x4 __attribute__((ext_vector_type(4)));

__device__ __forceinline__ void gload_lds16(const _Float16* g, void* lds) {
    __builtin_amdgcn_global_load_lds((const __attribute__((address_space(1))) void*)g,
                                     (__attribute__((address_space(3))) void*)lds, 16, 0, 0);
}

__device__ __forceinline__ float dot2acc(f16x2 a, f16x2 b, float c) {
#if __has_builtin(__builtin_amdgcn_fdot2)
    return __builtin_amdgcn_fdot2(a, b, c, false);
#else
    return c + (float)a[0] * (float)b[0] + (float)a[1] * (float)b[1];
#endif
}

// ---------------------------------------------------------------------------
// Kernel 1: per (b,h), 64-row tile: Wh = h_tile @ W[h]  (fp32 vector GEMM)
// Outputs: Wh_t fp16 [bh][c][n], f'=(Wh.a1)*log2e, g'=(Wh.a2)*log2e.
// ---------------------------------------------------------------------------
__global__ __launch_bounds__(256) void k_wh(
    const float* __restrict__ hsrc, const float* __restrict__ W,
    const float* __restrict__ a,
    _Float16* __restrict__ Wh_t, float* __restrict__ fb, float* __restrict__ gb)
{
    const int bid  = blockIdx.x;
    const int tile = bid & 63;
    const int bh   = bid >> 6;
    const int hh   = bh & 7;
    const int b    = bh >> 3;
    const int n0   = tile * 64;
    const int t    = threadIdx.x;

    __shared__ float Wl[64 * 68];   // [k][c] pad 68
    __shared__ float ht[64 * 68];   // [r][k] pad 68; reused as fp16 wt[c][64]
    __shared__ float red[2 * 64 * 16];

    {
        const float* Wg = W + hh * 4096;
        #pragma unroll
        for (int p = 0; p < 4; p++) {
            int idx = (t + p * 256) * 4;
            float4 v = *(const float4*)(Wg + idx);
            int k = idx >> 6, c = idx & 63;
            *(float4*)(&Wl[k * 68 + c]) = v;
        }
    }
    {
        #pragma unroll
        for (int p = 0; p < 4; p++) {
            int idx = t + p * 256;
            int r = idx >> 4, kq = (idx & 15) * 4;
            float4 v = *(const float4*)(hsrc + ((size_t)(b * NN + n0 + r)) * 512 + hh * 64 + kq);
            *(float4*)(&ht[r * 68 + kq]) = v;
        }
    }
    __syncthreads();

    const int rq = t >> 4, cq = t & 15;
    float acc[4][4] = {};
    for (int k = 0; k < 64; k++) {
        float4 wv = *(const float4*)(&Wl[k * 68 + cq * 4]);
        float hv[4];
        #pragma unroll
        for (int i = 0; i < 4; i++) hv[i] = ht[(rq * 4 + i) * 68 + k];
        const float* wp = (const float*)&wv;
        #pragma unroll
        for (int i = 0; i < 4; i++)
            #pragma unroll
            for (int j = 0; j < 4; j++)
                acc[i][j] = fmaf(hv[i], wp[j], acc[i][j]);
    }

    float a1v[4], a2v[4];
    {
        const float* ag = a + hh * 128;
        #pragma unroll
        for (int j = 0; j < 4; j++) { a1v[j] = ag[cq * 4 + j]; a2v[j] = ag[64 + cq * 4 + j]; }
    }
    __syncthreads();

    _Float16* wt = (_Float16*)ht;    // [c][64 rows]
    #pragma unroll
    for (int i = 0; i < 4; i++) {
        float fp = 0.f, gp = 0.f;
        #pragma unroll
        for (int j = 0; j < 4; j++) {
            fp = fmaf(acc[i][j], a1v[j], fp);
            gp = fmaf(acc[i][j], a2v[j], gp);
        }
        red[0 * 1024 + (rq * 4 + i) * 16 + cq] = fp;
        red[1 * 1024 + (rq * 4 + i) * 16 + cq] = gp;
        #pragma unroll
        for (int j = 0; j < 4; j++)
            wt[(cq * 4 + j) * 64 + rq * 4 + i] = (_Float16)acc[i][j];
    }
    __syncthreads();

    if (t < 128) {
        int which = t >> 6, row = t & 63;
        const float* rr = &red[which * 1024 + row * 16];
        float s = 0.f;
        #pragma unroll
        for (int j = 0; j < 16; j++) s += rr[j];
        s *= LOG2E;
        float* dst = which ? gb : fb;
        dst[(size_t)bh * NN + n0 + row] = s;
    }
    #pragma unroll
    for (int p = 0; p < 2; p++) {
        int idx = t + p * 256;
        int c = idx >> 3, seg = idx & 7;
        float4 v = *(const float4*)(&wt[c * 64 + seg * 8]);
        *(float4*)(Wh_t + (size_t)bh * 64 * NN + (size_t)c * NN + n0 + seg * 8) = v;
    }
}

// ---------------------------------------------------------------------------
// Kernel prep: per bh: G = max g'; Eg = 2^(g-G), Fg = 2^(alpha*(g-G)) fp16.
// ---------------------------------------------------------------------------
__global__ __launch_bounds__(256) void k_prep(const float* __restrict__ gball,
                                              float* __restrict__ G,
                                              char* __restrict__ egfg_base)
{
    int bh = blockIdx.x, t = threadIdx.x;
    const float* g = gball + (size_t)bh * NN;
    float vals[16];
    float m = -1e30f;
    #pragma unroll
    for (int j = 0; j < 16; j++) { vals[j] = g[t + j * 256]; m = fmaxf(m, vals[j]); }
    #pragma unroll
    for (int s = 1; s < 64; s <<= 1) m = fmaxf(m, __shfl_xor(m, s, 64));
    __shared__ float wm[4];
    if ((t & 63) == 0) wm[t >> 6] = m;
    __syncthreads();
    float Gv = fmaxf(fmaxf(wm[0], wm[1]), fmaxf(wm[2], wm[3]));
    if (t == 0) G[bh] = Gv;
    _Float16* Eg = (_Float16*)(egfg_base + (size_t)bh * 16384);
    _Float16* Fg = Eg + NN;
    #pragma unroll
    for (int j = 0; j < 16; j++) {
        int i = t + j * 256;
        float d = vals[j] - Gv;
        Eg[i] = (_Float16)exp2f(d);
        Fg[i] = (_Float16)exp2f(ALPHA * d);
    }
}

// ---------------------------------------------------------------------------
// Kernel 2: attention, k-split design.
// 512 blocks x 512 thr. Block: 128 rows x 64 cols. Wave w: kg=w>>1 (m-range
// kg*1024..+1024), wr=w&1 (rows wr*64..+64). 16 supersteps; per ss each wave
// consumes its kg's 64-m tile. 4-tile double-buffered LDS via global_load_lds
// (XOR granule swizzle, verified conflict-free). Epilogue: kg-partials reduced
// through LDS (3 rounds), denominators via dn[4][128] (aliased into Bt).
// ---------------------------------------------------------------------------
__global__ __launch_bounds__(512, 4) void k_attn(
    const _Float16* __restrict__ Wh_t, const float* __restrict__ fb,
    const float* __restrict__ G, const char* __restrict__ egfg_base,
    float* __restrict__ out)
{
    // XCD-bijective swizzle: 512 = 8 XCD x 64; XCD x owns 2 full bh slices.
    const int orig  = blockIdx.x;
    const int bid   = (orig & 7) * 64 + (orig >> 3);
    const int ntile = bid & 31;
    const int bh    = bid >> 5;
    const int hh    = bh & 7;
    const int b     = bh >> 3;
    const int n0    = ntile * 128;
    const int t     = threadIdx.x;
    const int w     = t >> 6;
    const int l     = t & 63;
    const int kg    = w >> 1;        // 0..3 m-split
    const int wr    = w & 1;         // 0..1 row-split
    const int lr    = l & 15;
    const int lg    = l >> 4;

    const _Float16* Wp  = Wh_t + (size_t)bh * 64 * NN;
    const _Float16* Egp = (const _Float16*)(egfg_base + (size_t)bh * 16384);
    const float     Gv  = G[bh];

    __shared__ _Float16 __attribute__((aligned(16))) Bt[2][4][4096];  // 64 KB

    // per-row factors (one of Ef,Ff is exactly 1)
    f16x2 ef2[4], ff2[4];
    #pragma unroll
    for (int rg = 0; rg < 4; rg++) {
        int rn = n0 + wr * 64 + rg * 16 + lr;
        float s  = fb[(size_t)bh * NN + rn] + Gv;
        float t1 = (1.f - ALPHA) * s;
        _Float16 e = (_Float16)exp2f(fminf(t1, 0.f));
        _Float16 f = (_Float16)exp2f(fminf(-t1, 0.f));
        ef2[rg] = (f16x2){e, e};
        ff2[rg] = (f16x2){f, f};
    }
    const f16x2 one2 = (f16x2){(_Float16)1.0f, (_Float16)1.0f};

    f32x4 acc[4][4];
    #pragma unroll
    for (int rg = 0; rg < 4; rg++)
        #pragma unroll
        for (int ct = 0; ct < 4; ct++) acc[rg][ct] = (f32x4){0.f, 0.f, 0.f, 0.f};
    float dsum[4] = {0.f, 0.f, 0.f, 0.f};

    // staging: tile tk = w>>1 staged by wave-pair (w&1); thread handles
    // granules g = (w&1)*64 + lane + p*128, p=0..3. Source XOR-swizzled.
    const int tk_s = w >> 1;
    int goff[4], ldof[4];
    #pragma unroll
    for (int p = 0; p < 4; p++) {
        int g  = (w & 1) * 64 + l + p * 128;
        int c  = g >> 3, sl = g & 7;
        int gi = sl ^ (c & 7);
        goff[p] = c * NN + gi * 8;                 // + mbase
        ldof[p] = ((w & 1) * 64 + p * 128) * 8;    // halves; +lane*16B by HW
    }
    _Float16* tbase = &Bt[0][tk_s][0];

    #define STAGE(nb, ss)                                                       \
        {                                                                        \
            int mb = tk_s * 1024 + (ss) * 64;                                    \
            _Float16* dst = tbase + (nb) * 16384;                                \
            gload_lds16(Wp + mb + goff[0], (void*)(dst + ldof[0]));              \
            gload_lds16(Wp + mb + goff[1], (void*)(dst + ldof[1]));              \
            gload_lds16(Wp + mb + goff[2], (void*)(dst + ldof[2]));              \
            gload_lds16(Wp + mb + goff[3], (void*)(dst + ldof[3]));              \
        }

    STAGE(0, 0);
    __syncthreads();

    for (int ss = 0; ss < 16; ss++) {
        const int cur = ss & 1;
        if (ss < 15) STAGE(cur ^ 1, ss + 1);

        const _Float16* bt = &Bt[cur][kg][0];
        const int mglob = kg * 1024 + ss * 64;

        #pragma unroll
        for (int kh = 0; kh < 2; kh++) {
            f16x8 bfr[4];
            #pragma unroll
            for (int ct = 0; ct < 4; ct++) {
                int cl   = ct * 16 + lr;
                int slot = (kh * 4 + lg) ^ (cl & 7);
                bfr[ct] = *(const f16x8*)(bt + cl * 64 + slot * 8);
            }
            const _Float16* ep = Egp + mglob + kh * 32 + lg * 8;
            f16x8 eg8 = *(const f16x8*)ep;
            f16x8 fg8 = *(const f16x8*)(ep + NN);

            #pragma unroll
            for (int rg = 0; rg < 4; rg++) {
                f16x8 af;
                float ds = dsum[rg];
                #pragma unroll
                for (int d = 0; d < 4; d++) {
                    f16x2 e2 = ((const f16x2*)&eg8)[d];
                    f16x2 f2 = ((const f16x2*)&fg8)[d];
                    f16x2 p2 = __builtin_elementwise_max(e2 * ef2[rg], f2 * ff2[rg]);
                    ((f16x2*)&af)[d] = p2;
                    ds = dot2acc(p2, one2, ds);
                }
                dsum[rg] = ds;
                #pragma unroll
                for (int ct = 0; ct < 4; ct++)
                    acc[rg][ct] = __builtin_amdgcn_mfma_f32_16x16x32_f16(
                        af, bfr[ct], acc[rg][ct], 0, 0, 0);
            }
        }
        __syncthreads();
    }
    #undef STAGE

    // ---------------- epilogue: kg-reduction ----------------
    // dn[4][128] + dnS[128] aliased at Bt+32KB; R regions [wr] at 0/16KB.
    float* dnP = (float*)((char*)Bt + 32768);
    float* dnS = dnP + 512;
    f32x4* Rw  = (f32x4*)((char*)Bt + wr * 16384);

    // per-row denominator partials (reduce lg groups in-wave)
    #pragma unroll
    for (int rg = 0; rg < 4; rg++) {
        float d = dsum[rg];
        d += __shfl_xor(d, 16, 64);
        d += __shfl_xor(d, 32, 64);
        if (lg == 0) dnP[kg * 128 + wr * 64 + rg * 16 + lr] = d;
    }

    #define WRITE_R()                                                            \
        { _Pragma("unroll") for (int rg = 0; rg < 4; rg++)                       \
          _Pragma("unroll") for (int ct = 0; ct < 4; ct++)                       \
            Rw[(rg * 4 + ct) * 64 + l] = acc[rg][ct]; }
    #define ADD_R()                                                              \
        { _Pragma("unroll") for (int rg = 0; rg < 4; rg++)                       \
          _Pragma("unroll") for (int ct = 0; ct < 4; ct++)                       \
            acc[rg][ct] += Rw[(rg * 4 + ct) * 64 + l]; }

    if (kg == 1) WRITE_R();
    __syncthreads();
    if (t < 128) dnS[t] = dnP[t] + dnP[128 + t] + dnP[256 + t] + dnP[384 + t];
    if (kg == 0) ADD_R();
    __syncthreads();
    if (kg == 2) WRITE_R();
    __syncthreads();
    if (kg == 0) ADD_R();
    __syncthreads();
    if (kg == 3) WRITE_R();
    __syncthreads();

    if (kg == 0) {
        ADD_R();
        float* outp = out + ((size_t)(b * NN + n0)) * 512 + hh * 64;
        #pragma unroll
        for (int rg = 0; rg < 4; rg++)
            #pragma unroll
            for (int reg = 0; reg < 4; reg++) {
                int row = wr * 64 + rg * 16 + lg * 4 + reg;
                float rinv = 1.0f / dnS[row];
                #pragma unroll
                for (int ct = 0; ct < 4; ct++) {
                    float v = acc[rg][ct][reg] * rinv;
                    v = v > 0.f ? v : (exp2f(v * LOG2E) - 1.f);   // elu
                    outp[(size_t)row * 512 + ct * 16 + lr] = v;
                }
            }
    }
    #undef WRITE_R
    #undef ADD_R
}

// ---------------------------------------------------------------------------
extern "C" void kernel_launch(void* const* d_in, const int* in_sizes, int n_in,
                              void* d_out, int out_size, void* d_ws, size_t ws_size,
                              hipStream_t stream)
{
    const float* hsrc = (const float*)d_in[0];
    const float* W    = (const float*)d_in[1];
    const float* a    = (const float*)d_in[2];
    float* outp       = (float*)d_out;

    const size_t WHT_BYTES = (size_t)NB * NH * 64 * NN * sizeof(_Float16); // 8 MB
    const size_t FB_BYTES  = (size_t)NB * NH * NN * sizeof(float);         // 256 KB
    const size_t GB_BYTES  = (size_t)NB * NH * NN * sizeof(float);         // 256 KB
    const size_t NEED = WHT_BYTES + FB_BYTES + GB_BYTES + 64 * sizeof(float);
    if (ws_size < NEED) return;

    char* ws = (char*)d_ws;
    _Float16* Wh_t = (_Float16*)ws;
    float*    fbuf = (float*)(ws + WHT_BYTES);
    char*     gbase = ws + WHT_BYTES + FB_BYTES;   // g' f32 -> Eg|Fg fp16 (aliased)
    float*    Gmax = (float*)(ws + WHT_BYTES + FB_BYTES + GB_BYTES);

    k_wh  <<<dim3(NB * NH * (NN / 64)),  dim3(256), 0, stream>>>(hsrc, W, a, Wh_t, fbuf, (float*)gbase);
    k_prep<<<dim3(NB * NH),              dim3(256), 0, stream>>>((const float*)gbase, Gmax, gbase);
    k_attn<<<dim3(NB * NH * (NN / 128)), dim3(512), 0, stream>>>(Wh_t, fbuf, Gmax, gbase, outp);
}